// Round 1
// baseline (1177.415 us; speedup 1.0000x reference)
//
#include <hip/hip_runtime.h>
#include <hip/hip_bf16.h>

typedef __attribute__((ext_vector_type(8))) short short8;   // 8 bf16 (4 VGPR) MFMA A/B frag
typedef __attribute__((ext_vector_type(4))) short short4v;  // 4 bf16 (8B)
typedef __attribute__((ext_vector_type(4))) float f32x4;    // MFMA C/D frag

#define D_IN 1280
#define D_OUT 1280
#define RANK 4
#define LORA_STRIDE 4
#define BM 128
#define BN 128
#define BK 64

// fp32 -> bf16 round-to-nearest-even, bit-cast to short for LDS storage
__device__ __forceinline__ short f2bs(float f) {
    __hip_bfloat16 h = __float2bfloat16(f);
    return __builtin_bit_cast(short, h);
}

// LDS layout: row-major [row][64 bf16], 16-B chunk index XORed with (row&7)
// to spread banks for both ds_write_b128/b64 staging and b128 frag reads.
__device__ __forceinline__ int swz(int row, int k) {
    return row * BK + ((((k >> 3) ^ row) & 7) << 3) + (k & 7);
}

__global__ __launch_bounds__(256, 2)
void lora_fused_gemm(const float* __restrict__ x,      // [M][D_IN]
                     const int* __restrict__ lora_id,  // [G]
                     const float* __restrict__ W,      // [D_OUT][D_IN]
                     const float* __restrict__ Wd,     // [L][RANK][D_IN]
                     const float* __restrict__ Wu,     // [L][D_OUT][RANK]
                     float* __restrict__ out,          // [M][D_OUT]
                     int t_len, int ntiles_n) {
    __shared__ short sA[BM * BK];  // 16 KB
    __shared__ short sB[BN * BK];  // 16 KB

    const int tid = threadIdx.x;
    const int bx = blockIdx.x;
    const int ntile = bx % ntiles_n;   // n fast: blocks sharing an m-tile run close -> x reuse in L2/L3
    const int mtile = bx / ntiles_n;
    const int gm = mtile * BM;
    const int gn = ntile * BN;

    const int chunk = gm / t_len;      // block-uniform (BM divides t_len)
    const int lid_raw = lora_id[chunk];
    const bool active = lid_raw >= 0;
    const int idx = active ? (lid_raw / LORA_STRIDE) : 0;
    const float lscale = active ? 1.0f : 0.0f;  // SCALE = 1.0

    // ---- A staging mapping: thread -> (row = tid>>1, 32 contiguous k at (tid&1)*32) ----
    const int arow = tid >> 1;
    const int acol = (tid & 1) * 32;
    const float* xp = x + (long)(gm + arow) * D_IN + acol;

    // ---- B staging mapping: thread -> (k-group kg of 4, rows nr+16s, s=0..7) ----
    const int kg = tid & 15;
    const int nr = tid >> 4;
    const float* wp = W + (long)gn * D_IN + kg * 4;
    const float* wdp = Wd + (long)idx * RANK * D_IN + kg * 4;

    // Wu columns for this thread's 8 n-rows: fixed over the K-loop; pre-scale by active flag
    f32x4 u[8];
    #pragma unroll
    for (int s = 0; s < 8; ++s) {
        f32x4 t = *reinterpret_cast<const f32x4*>(
            Wu + ((long)idx * D_OUT + gn + nr + 16 * s) * RANK);
        #pragma unroll
        for (int j = 0; j < 4; ++j) u[s][j] = t[j] * lscale;
    }

    // ---- MFMA wave layout: 2x2 waves, each 64x64 = 4x4 tiles of 16x16 ----
    const int wave = tid >> 6;
    const int lane = tid & 63;
    const int wm = (wave & 1) * 64;
    const int wn = (wave >> 1) * 64;
    const int quad = lane >> 4;
    const int lr = lane & 15;

    f32x4 acc[4][4];
    #pragma unroll
    for (int a = 0; a < 4; ++a)
        #pragma unroll
        for (int b = 0; b < 4; ++b)
            #pragma unroll
            for (int j = 0; j < 4; ++j) acc[a][b][j] = 0.f;

    for (int k0 = 0; k0 < D_IN; k0 += BK) {
        if (k0) __syncthreads();  // protect LDS from overwrite while previous MFMAs read

        // ---- stage A: x fp32 -> bf16 -> LDS (128x64) ----
        f32x4 xv[8];
        #pragma unroll
        for (int q = 0; q < 8; ++q)
            xv[q] = *reinterpret_cast<const f32x4*>(xp + k0 + q * 4);
        #pragma unroll
        for (int q = 0; q < 4; ++q) {
            short8 v;
            #pragma unroll
            for (int j = 0; j < 4; ++j) {
                v[j]     = f2bs(xv[2 * q][j]);
                v[j + 4] = f2bs(xv[2 * q + 1][j]);
            }
            *reinterpret_cast<short8*>(&sA[swz(arow, acol + q * 8)]) = v;
        }

        // ---- stage B: W_eff = W + (Wu*lscale) @ Wd, fp32, -> bf16 -> LDS (128x64) ----
        f32x4 wd[RANK];
        #pragma unroll
        for (int r = 0; r < RANK; ++r)
            wd[r] = *reinterpret_cast<const f32x4*>(wdp + (long)r * D_IN + k0);
        #pragma unroll
        for (int s = 0; s < 8; ++s) {
            const int n = nr + 16 * s;
            f32x4 wv = *reinterpret_cast<const f32x4*>(wp + (long)n * D_IN + k0);
            short4v e;
            #pragma unroll
            for (int j = 0; j < 4; ++j) {
                float v = wv[j] + u[s][0] * wd[0][j] + u[s][1] * wd[1][j]
                                + u[s][2] * wd[2][j] + u[s][3] * wd[3][j];
                e[j] = f2bs(v);
            }
            *reinterpret_cast<short4v*>(&sB[swz(n, kg * 4)]) = e;
        }

        __syncthreads();

        // ---- MFMA inner loop: 2 k-steps of 32, 16 MFMAs each ----
        #pragma unroll
        for (int ks = 0; ks < 2; ++ks) {
            short8 af[4], bfr[4];
            #pragma unroll
            for (int mi = 0; mi < 4; ++mi)
                af[mi] = *reinterpret_cast<const short8*>(
                    &sA[swz(wm + mi * 16 + lr, ks * 32 + quad * 8)]);
            #pragma unroll
            for (int ni = 0; ni < 4; ++ni)
                bfr[ni] = *reinterpret_cast<const short8*>(
                    &sB[swz(wn + ni * 16 + lr, ks * 32 + quad * 8)]);
            #pragma unroll
            for (int mi = 0; mi < 4; ++mi)
                #pragma unroll
                for (int ni = 0; ni < 4; ++ni)
                    acc[mi][ni] = __builtin_amdgcn_mfma_f32_16x16x32_bf16(
                        af[mi], bfr[ni], acc[mi][ni], 0, 0, 0);
        }
    }

    // ---- epilogue: C/D layout col=lane&15, row=quad*4+reg (m89-verified) ----
    #pragma unroll
    for (int mi = 0; mi < 4; ++mi) {
        #pragma unroll
        for (int ni = 0; ni < 4; ++ni) {
            float* op = out + (long)(gm + wm + mi * 16 + quad * 4) * D_OUT
                            + gn + wn + ni * 16 + lr;
            #pragma unroll
            for (int j = 0; j < 4; ++j) op[(long)j * D_OUT] = acc[mi][ni][j];
        }
    }
}

extern "C" void kernel_launch(void* const* d_in, const int* in_sizes, int n_in,
                              void* d_out, int out_size, void* d_ws, size_t ws_size,
                              hipStream_t stream) {
    const float* x   = (const float*)d_in[0];
    const int* lid   = (const int*)d_in[1];
    const float* W   = (const float*)d_in[2];
    const float* Wd  = (const float*)d_in[3];
    const float* Wu  = (const float*)d_in[4];
    float* out       = (float*)d_out;

    const int M = in_sizes[0] / D_IN;     // 65536
    const int G = in_sizes[1];            // 16
    const int t_len = M / G;              // 4096 (BM divides it)
    const int ntiles_n = D_OUT / BN;      // 10
    const int nblocks = (M / BM) * ntiles_n;  // 5120

    lora_fused_gemm<<<nblocks, 256, 0, stream>>>(x, lid, W, Wd, Wu, out, t_len, ntiles_n);
}